// Round 2
// baseline (216.340 us; speedup 1.0000x reference)
//
#include <hip/hip_runtime.h>

typedef __attribute__((ext_vector_type(8))) short short8;
typedef __attribute__((ext_vector_type(4))) float f32x4;

#define MFMA16(a, b, c) __builtin_amdgcn_mfma_f32_16x16x32_bf16((a), (b), (c), 0, 0, 0)

__device__ __forceinline__ unsigned short f2bf(float f) {
  unsigned int u = __float_as_uint(f);
  u += 0x7FFFu + ((u >> 16) & 1u);   // RNE; inputs finite
  return (unsigned short)(u >> 16);
}

__device__ __forceinline__ void gload16(const void* g, void* l) {
  __builtin_amdgcn_global_load_lds((const __attribute__((address_space(1))) void*)g,
                                   (__attribute__((address_space(3))) void*)l, 16, 0, 0);
}

// Read one MFMA operand fragment (8 bf16 along K) from a 64-elem-row (128B) LDS tile
// staged with the source-side XOR swizzle: LDS(row,cc) holds global chunk cc^(row&7).
__device__ __forceinline__ short8 fragld64(const unsigned short* base, int row, int kchunk) {
  int cc = kchunk ^ (row & 7);
  return *(const short8*)(base + row * 64 + cc * 8);
}

__global__ void cvtk(const float* __restrict__ in, unsigned short* __restrict__ out, int n4) {
  int i = blockIdx.x * blockDim.x + threadIdx.x;
  if (i >= n4) return;
  float4 v = ((const float4*)in)[i];
  ushort4 o;
  o.x = f2bf(v.x); o.y = f2bf(v.y); o.z = f2bf(v.z); o.w = f2bf(v.w);
  ((ushort4*)out)[i] = o;
}

// C[M=4096][N=1024] = A[M][K=1024] * B[N][K]^T + bias, optional scale, bf16 or f32 out.
// grid: (N/128, M/128, nmat). 256 threads, 4 waves in 2x2, each wave 64x64 (4x4 frags).
template<bool OUT_BF16>
__global__ __launch_bounds__(256, 3) void gemm_bt(
    const unsigned short* __restrict__ Abase, const unsigned short* __restrict__ Bbase,
    const float* __restrict__ bias0, const float* __restrict__ bias1,
    const float* __restrict__ bias2, void* __restrict__ outv, float scale0)
{
  constexpr int K = 1024, N = 1024;
  const int z = blockIdx.z;
  const unsigned short* A = Abase + (size_t)z * 4194304ull;
  const unsigned short* B = Bbase + (size_t)z * 1048576ull;
  const float* bias = (z == 0) ? bias0 : ((z == 1) ? bias1 : bias2);
  const float scale = (z == 0) ? scale0 : 1.0f;

  __shared__ unsigned short ldsA[128 * 64];
  __shared__ unsigned short ldsB[128 * 64];

  const int tid = threadIdx.x;
  const int lane = tid & 63, wid = tid >> 6;
  const int c16 = lane & 15, g = lane >> 4;
  const int m0 = blockIdx.y * 128, n0 = blockIdx.x * 128;
  const int wr = (wid >> 1) * 64, wc = (wid & 1) * 64;

  f32x4 acc[4][4] = {};

  for (int kt = 0; kt < K; kt += 64) {
    __syncthreads();
#pragma unroll
    for (int i = 0; i < 4; ++i) {
      int row = i * 32 + (tid >> 3);
      int cc = tid & 7;
      int scc = cc ^ (row & 7);
      gload16(A + (size_t)(m0 + row) * K + kt + scc * 8, ldsA + row * 64 + cc * 8);
      gload16(B + (size_t)(n0 + row) * K + kt + scc * 8, ldsB + row * 64 + cc * 8);
    }
    __syncthreads();
#pragma unroll
    for (int kc = 0; kc < 2; ++kc) {
      short8 af[4], bf[4];
#pragma unroll
      for (int mi = 0; mi < 4; ++mi) af[mi] = fragld64(ldsA, wr + mi * 16 + c16, kc * 4 + g);
#pragma unroll
      for (int ni = 0; ni < 4; ++ni) bf[ni] = fragld64(ldsB, wc + ni * 16 + c16, kc * 4 + g);
#pragma unroll
      for (int mi = 0; mi < 4; ++mi)
#pragma unroll
        for (int ni = 0; ni < 4; ++ni)
          acc[mi][ni] = MFMA16(af[mi], bf[ni], acc[mi][ni]);
    }
  }

#pragma unroll
  for (int mi = 0; mi < 4; ++mi)
#pragma unroll
    for (int ni = 0; ni < 4; ++ni) {
      int col = n0 + wc + ni * 16 + c16;
      float bb = bias[col];
#pragma unroll
      for (int r = 0; r < 4; ++r) {
        int row = m0 + wr + mi * 16 + g * 4 + r;
        float v = (acc[mi][ni][r] + bb) * scale;
        if constexpr (OUT_BF16)
          ((unsigned short*)outv)[(size_t)z * 4194304ull + (size_t)row * N + col] = f2bf(v);
        else
          ((float*)outv)[(size_t)row * N + col] = v;
      }
    }
}

// Flash attention: grid (sl/64, H, B); 4 waves, wave w owns q rows [q0+16w, q0+16w+16).
// qh/kh/vh layout: [b][s][h][dk] bf16 (Q pre-scaled by 1/8 in projection).
__global__ __launch_bounds__(256, 3) void attn(
    const unsigned short* __restrict__ qh, const unsigned short* __restrict__ kh,
    const unsigned short* __restrict__ vh, const int* __restrict__ mask,
    unsigned short* __restrict__ zout)
{
  constexpr int SL = 2048, DM = 1024;
  const int q0 = blockIdx.x * 64;
  const int h = blockIdx.y, b = blockIdx.z;
  const int tid = threadIdx.x, lane = tid & 63, w = tid >> 6;
  const int c16 = lane & 15, g = lane >> 4;

  __shared__ unsigned short kbuf[64 * 64];    // [key][d], xor-swizzled chunks
  __shared__ unsigned short vt[64 * 72];      // [d][key], stride 72 (144B, 16B aligned)
  __shared__ unsigned short pbuf[4][16 * 72]; // per-wave P rows, stride 72

  const size_t qoff = ((size_t)b * SL + q0 + w * 16 + c16) * DM + (size_t)h * 64;
  short8 qf0 = *(const short8*)(qh + qoff + g * 8);
  short8 qf1 = *(const short8*)(qh + qoff + 32 + g * 8);

  f32x4 zacc[4] = {};
  float mrun[4], lrun[4];
#pragma unroll
  for (int r = 0; r < 4; ++r) { mrun[r] = -INFINITY; lrun[r] = 0.f; }

  const size_t kvbase = (size_t)b * SL * DM + (size_t)h * 64;
  const int* mrow = mask + ((size_t)b * SL + q0 + w * 16) * SL;  // int32 bool
  unsigned short* pb = pbuf[w];

  for (int kt = 0; kt < SL; kt += 64) {
    __syncthreads();
    // stage K tile (64 x 64 bf16) via global_load_lds, source-swizzled
#pragma unroll
    for (int i = 0; i < 2; ++i) {
      int row = i * 32 + (tid >> 3);
      int cc = tid & 7, scc = cc ^ (row & 7);
      gload16(kh + kvbase + (size_t)(kt + row) * DM + scc * 8, kbuf + row * 64 + cc * 8);
    }
    // stage V transposed: thread reads 8 contiguous d of one key row, writes column j
#pragma unroll
    for (int i = 0; i < 2; ++i) {
      int j = (tid & 31) + i * 32;
      int d0 = (tid >> 5) * 8;
      short8 vv = *(const short8*)(vh + kvbase + (size_t)(kt + j) * DM + d0);
#pragma unroll
      for (int e = 0; e < 8; ++e) vt[(d0 + e) * 72 + j] = (unsigned short)vv[e];
    }
    __syncthreads();

    // S = Q * K^T  (C: row=q=(g*4+r), col=key=c16 within 16x16 tile nt)
    f32x4 sacc[4] = {};
#pragma unroll
    for (int kc = 0; kc < 2; ++kc) {
      short8 qf = kc ? qf1 : qf0;
#pragma unroll
      for (int nt = 0; nt < 4; ++nt) {
        short8 kf = fragld64(kbuf, nt * 16 + c16, kc * 4 + g);
        sacc[nt] = MFMA16(qf, kf, sacc[nt]);
      }
    }
    // mask (True -> -1e10); mask shape [b][1][q][k], stored as int32
#pragma unroll
    for (int nt = 0; nt < 4; ++nt) {
      int col = kt + nt * 16 + c16;
#pragma unroll
      for (int r = 0; r < 4; ++r)
        if (mrow[(size_t)(g * 4 + r) * SL + col]) sacc[nt][r] = -1e10f;
    }
    // online softmax, per q-row (r): reduce across the 16 lanes of group g
#pragma unroll
    for (int r = 0; r < 4; ++r) {
      float mx = fmaxf(fmaxf(sacc[0][r], sacc[1][r]), fmaxf(sacc[2][r], sacc[3][r]));
      mx = fmaxf(mx, __shfl_xor(mx, 1));
      mx = fmaxf(mx, __shfl_xor(mx, 2));
      mx = fmaxf(mx, __shfl_xor(mx, 4));
      mx = fmaxf(mx, __shfl_xor(mx, 8));
      float mnew = fmaxf(mrun[r], mx);
      float alpha = __expf(mrun[r] - mnew);
      mrun[r] = mnew;
      float rs = 0.f;
#pragma unroll
      for (int nt = 0; nt < 4; ++nt) {
        float p = __expf(sacc[nt][r] - mnew);
        sacc[nt][r] = p;
        rs += p;
      }
      rs += __shfl_xor(rs, 1);
      rs += __shfl_xor(rs, 2);
      rs += __shfl_xor(rs, 4);
      rs += __shfl_xor(rs, 8);
      lrun[r] = lrun[r] * alpha + rs;
#pragma unroll
      for (int dt = 0; dt < 4; ++dt) zacc[dt][r] *= alpha;
    }
    // P -> bf16 via wave-private LDS (same-wave DS ops are program-ordered)
#pragma unroll
    for (int nt = 0; nt < 4; ++nt)
#pragma unroll
      for (int r = 0; r < 4; ++r)
        pb[(g * 4 + r) * 72 + nt * 16 + c16] = f2bf(sacc[nt][r]);
    // z += P * V
#pragma unroll
    for (int kc = 0; kc < 2; ++kc) {
      short8 pf = *(const short8*)(pb + c16 * 72 + kc * 32 + g * 8);
#pragma unroll
      for (int dt = 0; dt < 4; ++dt) {
        short8 vf = *(const short8*)(vt + (dt * 16 + c16) * 72 + kc * 32 + g * 8);
        zacc[dt] = MFMA16(pf, vf, zacc[dt]);
      }
    }
  }

  // z / l -> bf16, layout [b][s][h*64+d] (ready as A of the output GEMM)
#pragma unroll
  for (int r = 0; r < 4; ++r) {
    float inv = 1.f / lrun[r];
    size_t orow = ((size_t)b * SL + q0 + w * 16 + g * 4 + r) * DM + (size_t)h * 64;
#pragma unroll
    for (int dt = 0; dt < 4; ++dt)
      zout[orow + dt * 16 + c16] = f2bf(zacc[dt][r] * inv);
  }
}

extern "C" void kernel_launch(void* const* d_in, const int* in_sizes, int n_in,
                              void* d_out, int out_size, void* d_ws, size_t ws_size,
                              hipStream_t stream) {
  const float* q  = (const float*)d_in[0];
  const float* k  = (const float*)d_in[1];
  const float* v  = (const float*)d_in[2];
  const int* mask = (const int*)d_in[3];
  const float* Wq = (const float*)d_in[4];
  const float* bq = (const float*)d_in[5];
  const float* Wk = (const float*)d_in[6];
  const float* bk = (const float*)d_in[7];
  const float* Wv = (const float*)d_in[8];
  const float* bv = (const float*)d_in[9];
  const float* Wo = (const float*)d_in[10];
  const float* bo = (const float*)d_in[11];

  char* ws = (char*)d_ws;
  unsigned short* xbf = (unsigned short*)ws;              // q,k,v bf16: 3 * 4194304
  unsigned short* wbf = (unsigned short*)(ws + 25165824); // Wq,Wk,Wv,Wo bf16: 4 * 1048576
  unsigned short* qkv = (unsigned short*)(ws + 33554432); // qh,kh,vh bf16: 3 * 4194304
  unsigned short* zbf = (unsigned short*)(ws + 58720256); // z bf16: 4194304

  cvtk<<<4096, 256, 0, stream>>>(q, xbf, 1048576);
  cvtk<<<4096, 256, 0, stream>>>(k, xbf + 4194304ull, 1048576);
  cvtk<<<4096, 256, 0, stream>>>(v, xbf + 8388608ull, 1048576);
  cvtk<<<1024, 256, 0, stream>>>(Wq, wbf, 262144);
  cvtk<<<1024, 256, 0, stream>>>(Wk, wbf + 1048576ull, 262144);
  cvtk<<<1024, 256, 0, stream>>>(Wv, wbf + 2097152ull, 262144);
  cvtk<<<1024, 256, 0, stream>>>(Wo, wbf + 3145728ull, 262144);

  // fused Q/K/V projections; Q scaled by 1/sqrt(dk)=0.125 in epilogue
  gemm_bt<true><<<dim3(8, 32, 3), 256, 0, stream>>>(xbf, wbf, bq, bk, bv, (void*)qkv, 0.125f);
  attn<<<dim3(32, 16, 2), 256, 0, stream>>>(qkv, qkv + 4194304ull, qkv + 8388608ull, mask, zbf);
  gemm_bt<false><<<dim3(8, 32, 1), 256, 0, stream>>>(zbf, wbf + 3145728ull, bo, bo, bo, d_out, 1.0f);
}

// Round 3
// 183.355 us; speedup vs baseline: 1.1799x; 1.1799x over previous
//
#include <hip/hip_runtime.h>

typedef __attribute__((ext_vector_type(8))) short short8;
typedef __attribute__((ext_vector_type(4))) float f32x4;

#define MFMA16(a, b, c) __builtin_amdgcn_mfma_f32_16x16x32_bf16((a), (b), (c), 0, 0, 0)

#if __has_builtin(__builtin_amdgcn_exp2f)
#define EXP2(x) __builtin_amdgcn_exp2f(x)
#else
#define EXP2(x) __expf((x) * 0.6931471805599453f)
#endif

__device__ __forceinline__ unsigned short f2bf(float f) {
  unsigned int u = __float_as_uint(f);
  u += 0x7FFFu + ((u >> 16) & 1u);   // RNE; inputs finite
  return (unsigned short)(u >> 16);
}

__device__ __forceinline__ void gload16(const void* g, void* l) {
  __builtin_amdgcn_global_load_lds((const __attribute__((address_space(1))) void*)g,
                                   (__attribute__((address_space(3))) void*)l, 16, 0, 0);
}

// Read one MFMA operand fragment (8 bf16 along K) from a 64-elem-row (128B) LDS tile
// staged with the source-side XOR swizzle: LDS(row,cc) holds global chunk cc^(row&7).
__device__ __forceinline__ short8 fragld64(const unsigned short* base, int row, int kchunk) {
  int cc = kchunk ^ (row & 7);
  return *(const short8*)(base + row * 64 + cc * 8);
}

__global__ void cvt3(const float* __restrict__ a, const float* __restrict__ b,
                     const float* __restrict__ c, unsigned short* __restrict__ out, int n4) {
  const float* src = (blockIdx.z == 0) ? a : ((blockIdx.z == 1) ? b : c);
  int i = blockIdx.x * blockDim.x + threadIdx.x;
  if (i >= n4) return;
  float4 v = ((const float4*)src)[i];
  ushort4 o;
  o.x = f2bf(v.x); o.y = f2bf(v.y); o.z = f2bf(v.z); o.w = f2bf(v.w);
  ((ushort4*)(out + (size_t)blockIdx.z * (size_t)n4 * 4))[i] = o;
}

__global__ void cvt4(const float* __restrict__ a, const float* __restrict__ b,
                     const float* __restrict__ c, const float* __restrict__ d,
                     unsigned short* __restrict__ out, int n4) {
  const float* src = (blockIdx.z == 0) ? a : ((blockIdx.z == 1) ? b
                   : ((blockIdx.z == 2) ? c : d));
  int i = blockIdx.x * blockDim.x + threadIdx.x;
  if (i >= n4) return;
  float4 v = ((const float4*)src)[i];
  ushort4 o;
  o.x = f2bf(v.x); o.y = f2bf(v.y); o.z = f2bf(v.z); o.w = f2bf(v.w);
  ((ushort4*)(out + (size_t)blockIdx.z * (size_t)n4 * 4))[i] = o;
}

// mask [b][q][k] int32 -> additive-bias^T [b][k][q] u16 (top half of -1e10f or 0).
// grid: (k_tiles=32, q_tiles=32, b=2), 256 threads, 64x64 tile via LDS.
__global__ void maskT(const int* __restrict__ m, unsigned short* __restrict__ mt) {
  constexpr int SL = 2048;
  __shared__ float t[64][65];
  const int kx = blockIdx.x * 64, qx = blockIdx.y * 64, b = blockIdx.z;
  const int tid = threadIdx.x;
  const unsigned short NEGB = (unsigned short)(__float_as_uint(-1e10f) >> 16);
#pragma unroll
  for (int p = 0; p < 4; ++p) {
    int i = p * 16 + (tid >> 4);          // q row
    int j4 = (tid & 15) * 4;              // k col
    int4 mv = *(const int4*)(m + ((size_t)b * SL + qx + i) * SL + kx + j4);
    t[j4 + 0][i] = mv.x ? 1.f : 0.f;
    t[j4 + 1][i] = mv.y ? 1.f : 0.f;
    t[j4 + 2][i] = mv.z ? 1.f : 0.f;
    t[j4 + 3][i] = mv.w ? 1.f : 0.f;
  }
  __syncthreads();
#pragma unroll
  for (int p = 0; p < 4; ++p) {
    int i2 = p * 16 + (tid >> 4);         // k row
    int j4 = (tid & 15) * 4;              // q col
    ushort4 o;
    o.x = t[i2][j4 + 0] != 0.f ? NEGB : 0;
    o.y = t[i2][j4 + 1] != 0.f ? NEGB : 0;
    o.z = t[i2][j4 + 2] != 0.f ? NEGB : 0;
    o.w = t[i2][j4 + 3] != 0.f ? NEGB : 0;
    *(ushort4*)(mt + ((size_t)b * SL + kx + i2) * SL + qx + j4) = o;
  }
}

// C[M=4096][N=1024] = A[M][K=1024] * B[N][K]^T + bias, optional scale, bf16 or f32 out.
// grid: (N/128, M/128, nmat). 256 threads, 4 waves in 2x2, each wave 64x64 (4x4 frags).
template<bool OUT_BF16>
__global__ __launch_bounds__(256, 3) void gemm_bt(
    const unsigned short* __restrict__ Abase, const unsigned short* __restrict__ Bbase,
    const float* __restrict__ bias0, const float* __restrict__ bias1,
    const float* __restrict__ bias2, void* __restrict__ outv, float scale0)
{
  constexpr int K = 1024, N = 1024;
  const int z = blockIdx.z;
  const unsigned short* A = Abase + (size_t)z * 4194304ull;
  const unsigned short* B = Bbase + (size_t)z * 1048576ull;
  const float* bias = (z == 0) ? bias0 : ((z == 1) ? bias1 : bias2);
  const float scale = (z == 0) ? scale0 : 1.0f;

  __shared__ unsigned short ldsA[128 * 64];
  __shared__ unsigned short ldsB[128 * 64];

  const int tid = threadIdx.x;
  const int lane = tid & 63, wid = tid >> 6;
  const int c16 = lane & 15, g = lane >> 4;
  const int m0 = blockIdx.y * 128, n0 = blockIdx.x * 128;
  const int wr = (wid >> 1) * 64, wc = (wid & 1) * 64;

  f32x4 acc[4][4] = {};

  for (int kt = 0; kt < K; kt += 64) {
    __syncthreads();
#pragma unroll
    for (int i = 0; i < 4; ++i) {
      int row = i * 32 + (tid >> 3);
      int cc = tid & 7;
      int scc = cc ^ (row & 7);
      gload16(A + (size_t)(m0 + row) * K + kt + scc * 8, ldsA + row * 64 + cc * 8);
      gload16(B + (size_t)(n0 + row) * K + kt + scc * 8, ldsB + row * 64 + cc * 8);
    }
    __syncthreads();
#pragma unroll
    for (int kc = 0; kc < 2; ++kc) {
      short8 af[4], bf[4];
#pragma unroll
      for (int mi = 0; mi < 4; ++mi) af[mi] = fragld64(ldsA, wr + mi * 16 + c16, kc * 4 + g);
#pragma unroll
      for (int ni = 0; ni < 4; ++ni) bf[ni] = fragld64(ldsB, wc + ni * 16 + c16, kc * 4 + g);
#pragma unroll
      for (int mi = 0; mi < 4; ++mi)
#pragma unroll
        for (int ni = 0; ni < 4; ++ni)
          acc[mi][ni] = MFMA16(af[mi], bf[ni], acc[mi][ni]);
    }
  }

#pragma unroll
  for (int mi = 0; mi < 4; ++mi)
#pragma unroll
    for (int ni = 0; ni < 4; ++ni) {
      int col = n0 + wc + ni * 16 + c16;
      float bb = bias[col];
#pragma unroll
      for (int r = 0; r < 4; ++r) {
        int row = m0 + wr + mi * 16 + g * 4 + r;
        float v = (acc[mi][ni][r] + bb) * scale;
        if constexpr (OUT_BF16)
          ((unsigned short*)outv)[(size_t)z * 4194304ull + (size_t)row * N + col] = f2bf(v);
        else
          ((float*)outv)[(size_t)row * N + col] = v;
      }
    }
}

// Flash attention, swapped-QK^T softmax. grid (sl/64, H, B); 4 waves, wave w owns
// q rows [q0+16w, q0+16w+16). Q pre-scaled by 0.125*log2(e); softmax in exp2 domain.
// mbt: additive bias^T [b][k][q] u16 (top half of f32; -1e10 where masked).
__global__ __launch_bounds__(256, 4) void attn(
    const unsigned short* __restrict__ qh, const unsigned short* __restrict__ kh,
    const unsigned short* __restrict__ vh, const unsigned short* __restrict__ mbt,
    unsigned short* __restrict__ zout)
{
  constexpr int SL = 2048, DM = 1024;
  const int q0 = blockIdx.x * 64;
  const int h = blockIdx.y, b = blockIdx.z;
  const int tid = threadIdx.x, lane = tid & 63, w = tid >> 6;
  const int c16 = lane & 15, g = lane >> 4;

  __shared__ unsigned short kbuf[64 * 64];    // [key][d], xor-swizzled chunks
  __shared__ unsigned short vt[64 * 72];      // [d][key], stride 72
  __shared__ unsigned short pbuf[4][16 * 72]; // per-wave P rows [q][key], stride 72

  const int qg = q0 + w * 16 + c16;           // this lane's q column in S^T
  const size_t qoff = ((size_t)b * SL + qg) * DM + (size_t)h * 64;
  short8 qf0 = *(const short8*)(qh + qoff + g * 8);
  short8 qf1 = *(const short8*)(qh + qoff + 32 + g * 8);

  f32x4 zacc[4] = {};
  float mrun = -INFINITY, lrun = 0.f;

  const size_t kvbase = (size_t)b * SL * DM + (size_t)h * 64;
  const unsigned short* mb = mbt + (size_t)b * SL * SL + qg + (size_t)(g * 4) * SL;
  unsigned short* pb = pbuf[w];

  for (int kt = 0; kt < SL; kt += 64) {
    __syncthreads();
    // stage K tile (64x64 bf16) via global_load_lds, source-swizzled
#pragma unroll
    for (int i = 0; i < 2; ++i) {
      int row = i * 32 + (tid >> 3);
      int cc = tid & 7, scc = cc ^ (row & 7);
      gload16(kh + kvbase + (size_t)(kt + row) * DM + scc * 8, kbuf + row * 64 + cc * 8);
    }
    // stage V transposed (scalar writes)
#pragma unroll
    for (int i = 0; i < 2; ++i) {
      int j = (tid & 31) + i * 32;
      int d0 = (tid >> 5) * 8;
      short8 vv = *(const short8*)(vh + kvbase + (size_t)(kt + j) * DM + d0);
#pragma unroll
      for (int e = 0; e < 8; ++e) vt[(d0 + e) * 72 + j] = (unsigned short)vv[e];
    }
    // mask-bias C-init (global u16 loads, overlap with staging latency)
    f32x4 sacc[4];
    {
      const unsigned short* mbk = mb + (size_t)kt * SL;
#pragma unroll
      for (int nt = 0; nt < 4; ++nt)
#pragma unroll
        for (int r = 0; r < 4; ++r) {
          unsigned int u = mbk[(size_t)(nt * 16 + r) * SL];
          sacc[nt][r] = __uint_as_float(u << 16);
        }
    }
    __syncthreads();

    // S^T = K * Q^T + bias  (D: row=key=(g*4+r) within tile nt, col=q=c16)
#pragma unroll
    for (int kc = 0; kc < 2; ++kc) {
      short8 qf = kc ? qf1 : qf0;
#pragma unroll
      for (int nt = 0; nt < 4; ++nt) {
        short8 kf = fragld64(kbuf, nt * 16 + c16, kc * 4 + g);
        sacc[nt] = MFMA16(kf, qf, sacc[nt]);
      }
    }

    // online softmax: lane owns q=c16, 16 keys in-lane; butterfly across g groups
    float mx;
    {
      float a0 = fmaxf(fmaxf(sacc[0][0], sacc[0][1]), fmaxf(sacc[0][2], sacc[0][3]));
      float a1 = fmaxf(fmaxf(sacc[1][0], sacc[1][1]), fmaxf(sacc[1][2], sacc[1][3]));
      float a2 = fmaxf(fmaxf(sacc[2][0], sacc[2][1]), fmaxf(sacc[2][2], sacc[2][3]));
      float a3 = fmaxf(fmaxf(sacc[3][0], sacc[3][1]), fmaxf(sacc[3][2], sacc[3][3]));
      mx = fmaxf(fmaxf(a0, a1), fmaxf(a2, a3));
    }
    mx = fmaxf(mx, __shfl_xor(mx, 16));
    mx = fmaxf(mx, __shfl_xor(mx, 32));
    float mnew = fmaxf(mrun, mx);
    float alpha = EXP2(mrun - mnew);
    mrun = mnew;
    float rs;
    {
      float ps[4];
#pragma unroll
      for (int nt = 0; nt < 4; ++nt) {
        float p0 = EXP2(sacc[nt][0] - mnew);
        float p1 = EXP2(sacc[nt][1] - mnew);
        float p2 = EXP2(sacc[nt][2] - mnew);
        float p3 = EXP2(sacc[nt][3] - mnew);
        sacc[nt][0] = p0; sacc[nt][1] = p1; sacc[nt][2] = p2; sacc[nt][3] = p3;
        ps[nt] = (p0 + p1) + (p2 + p3);
      }
      rs = (ps[0] + ps[1]) + (ps[2] + ps[3]);
    }
    rs += __shfl_xor(rs, 16);
    rs += __shfl_xor(rs, 32);
    lrun = lrun * alpha + rs;

    // pack P^T -> pb[q=c16][key], paired b32 writes (same-wave DS ordering)
#pragma unroll
    for (int nt = 0; nt < 4; ++nt) {
      unsigned int lo = (unsigned int)f2bf(sacc[nt][0]) | ((unsigned int)f2bf(sacc[nt][1]) << 16);
      unsigned int hi = (unsigned int)f2bf(sacc[nt][2]) | ((unsigned int)f2bf(sacc[nt][3]) << 16);
      *(unsigned int*)(pb + c16 * 72 + nt * 16 + g * 4 + 0) = lo;
      *(unsigned int*)(pb + c16 * 72 + nt * 16 + g * 4 + 2) = hi;
    }

    // rescale zacc rows (q_local = g*4+r) by that q's alpha
#pragma unroll
    for (int r = 0; r < 4; ++r) {
      float ar = __shfl(alpha, g * 4 + r);
      zacc[0][r] *= ar; zacc[1][r] *= ar; zacc[2][r] *= ar; zacc[3][r] *= ar;
    }

    // z += P * V
#pragma unroll
    for (int kc = 0; kc < 2; ++kc) {
      short8 pf = *(const short8*)(pb + c16 * 72 + kc * 32 + g * 8);
#pragma unroll
      for (int dt = 0; dt < 4; ++dt) {
        short8 vf = *(const short8*)(vt + (dt * 16 + c16) * 72 + kc * 32 + g * 8);
        zacc[dt] = MFMA16(pf, vf, zacc[dt]);
      }
    }
  }

  // z / l -> bf16, layout [b][s][h*64+d]
  float invl = 1.f / lrun;
#pragma unroll
  for (int r = 0; r < 4; ++r) {
    float ir = __shfl(invl, g * 4 + r);
    size_t orow = ((size_t)b * SL + q0 + w * 16 + g * 4 + r) * DM + (size_t)h * 64;
#pragma unroll
    for (int dt = 0; dt < 4; ++dt)
      zout[orow + dt * 16 + c16] = f2bf(zacc[dt][r] * ir);
  }
}

extern "C" void kernel_launch(void* const* d_in, const int* in_sizes, int n_in,
                              void* d_out, int out_size, void* d_ws, size_t ws_size,
                              hipStream_t stream) {
  const float* q  = (const float*)d_in[0];
  const float* k  = (const float*)d_in[1];
  const float* v  = (const float*)d_in[2];
  const int* mask = (const int*)d_in[3];
  const float* Wq = (const float*)d_in[4];
  const float* bq = (const float*)d_in[5];
  const float* Wk = (const float*)d_in[6];
  const float* bk = (const float*)d_in[7];
  const float* Wv = (const float*)d_in[8];
  const float* bv = (const float*)d_in[9];
  const float* Wo = (const float*)d_in[10];
  const float* bo = (const float*)d_in[11];

  char* ws = (char*)d_ws;
  unsigned short* xbf = (unsigned short*)ws;              // q,k,v bf16: 24 MB (dead after QKV gemm)
  unsigned short* mbt = (unsigned short*)ws;              // bias^T u16: 16.7 MB (aliases xbf)
  unsigned short* wbf = (unsigned short*)(ws + 25165824); // Wq,Wk,Wv,Wo bf16: 8 MB
  unsigned short* qkv = (unsigned short*)(ws + 33554432); // qh,kh,vh bf16: 24 MB
  unsigned short* zbf = (unsigned short*)(ws + 58720256); // z bf16: 8 MB

  cvt3<<<dim3(4096, 1, 3), 256, 0, stream>>>(q, k, v, xbf, 1048576);
  cvt4<<<dim3(1024, 1, 4), 256, 0, stream>>>(Wq, Wk, Wv, Wo, wbf, 262144);

  // fused Q/K/V projections; Q scaled by 0.125*log2(e) (softmax in exp2 domain)
  gemm_bt<true><<<dim3(8, 32, 3), 256, 0, stream>>>(xbf, wbf, bq, bk, bv, (void*)qkv,
                                                    0.125f * 1.44269504088896f);
  // xbf now dead; build mask bias^T in its place
  maskT<<<dim3(32, 32, 2), 256, 0, stream>>>(mask, mbt);
  attn<<<dim3(32, 16, 2), 256, 0, stream>>>(qkv, qkv + 4194304ull, qkv + 8388608ull, mbt, zbf);
  gemm_bt<false><<<dim3(8, 32, 1), 256, 0, stream>>>(zbf, wbf + 3145728ull, bo, bo, bo, d_out, 1.0f);
}

// Round 4
// 182.092 us; speedup vs baseline: 1.1881x; 1.0069x over previous
//
#include <hip/hip_runtime.h>

typedef __attribute__((ext_vector_type(8))) short short8;
typedef __attribute__((ext_vector_type(4))) float f32x4;

#define MFMA16(a, b, c) __builtin_amdgcn_mfma_f32_16x16x32_bf16((a), (b), (c), 0, 0, 0)

#if __has_builtin(__builtin_amdgcn_exp2f)
#define EXP2(x) __builtin_amdgcn_exp2f(x)
#else
#define EXP2(x) __expf((x) * 0.6931471805599453f)
#endif

__device__ __forceinline__ unsigned short f2bf(float f) {
  unsigned int u = __float_as_uint(f);
  u += 0x7FFFu + ((u >> 16) & 1u);   // RNE; inputs finite
  return (unsigned short)(u >> 16);
}

__device__ __forceinline__ void gload16(const void* g, void* l) {
  __builtin_amdgcn_global_load_lds((const __attribute__((address_space(1))) void*)g,
                                   (__attribute__((address_space(3))) void*)l, 16, 0, 0);
}

// Fragment read from a 64-col (128B-row) LDS tile staged with the chunk-XOR swizzle:
// LDS(row, cc) holds the tile's chunk cc^(row&7). Bank-conflict-free (2-way) for
// lanes reading rows base+c16 at the same kchunk.
__device__ __forceinline__ short8 fragld64(const unsigned short* base, int row, int kchunk) {
  int cc = kchunk ^ (row & 7);
  return *(const short8*)(base + row * 64 + cc * 8);
}

__global__ void cvt3(const float* __restrict__ a, const float* __restrict__ b,
                     const float* __restrict__ c, unsigned short* __restrict__ out, int n4) {
  const float* src = (blockIdx.z == 0) ? a : ((blockIdx.z == 1) ? b : c);
  int i = blockIdx.x * blockDim.x + threadIdx.x;
  if (i >= n4) return;
  float4 v = ((const float4*)src)[i];
  ushort4 o;
  o.x = f2bf(v.x); o.y = f2bf(v.y); o.z = f2bf(v.z); o.w = f2bf(v.w);
  ((ushort4*)(out + (size_t)blockIdx.z * (size_t)n4 * 4))[i] = o;
}

__global__ void cvt4(const float* __restrict__ a, const float* __restrict__ b,
                     const float* __restrict__ c, const float* __restrict__ d,
                     unsigned short* __restrict__ out, int n4) {
  const float* src = (blockIdx.z == 0) ? a : ((blockIdx.z == 1) ? b
                   : ((blockIdx.z == 2) ? c : d));
  int i = blockIdx.x * blockDim.x + threadIdx.x;
  if (i >= n4) return;
  float4 v = ((const float4*)src)[i];
  ushort4 o;
  o.x = f2bf(v.x); o.y = f2bf(v.y); o.z = f2bf(v.z); o.w = f2bf(v.w);
  ((ushort4*)(out + (size_t)blockIdx.z * (size_t)n4 * 4))[i] = o;
}

// mask [b][q][k] int32 -> bitmask u64 words: mw[(b*2048+q)*32 + k/64], bit i = mask[k=64*w+i].
// Each wave ballots 64 ints -> one word; 4 words per wave.
__global__ void maskpack(const int* __restrict__ m, unsigned long long* __restrict__ mw) {
  const int lane = threadIdx.x & 63;
  const size_t wbase = ((size_t)blockIdx.x * (blockDim.x >> 6) + (threadIdx.x >> 6)) * 4ull;
#pragma unroll
  for (int u = 0; u < 4; ++u) {
    size_t word = wbase + u;
    int x = m[word * 64 + lane];
    unsigned long long bb = __ballot(x != 0);
    if (lane == 0) mw[word] = bb;
  }
}

// C[M=4096][N=1024] = A[M][K=1024] * B[N][K]^T + bias, optional scale, bf16 or f32 out.
template<bool OUT_BF16>
__global__ __launch_bounds__(256, 3) void gemm_bt(
    const unsigned short* __restrict__ Abase, const unsigned short* __restrict__ Bbase,
    const float* __restrict__ bias0, const float* __restrict__ bias1,
    const float* __restrict__ bias2, void* __restrict__ outv, float scale0)
{
  constexpr int K = 1024, N = 1024;
  const int z = blockIdx.z;
  const unsigned short* A = Abase + (size_t)z * 4194304ull;
  const unsigned short* B = Bbase + (size_t)z * 1048576ull;
  const float* bias = (z == 0) ? bias0 : ((z == 1) ? bias1 : bias2);
  const float scale = (z == 0) ? scale0 : 1.0f;

  __shared__ unsigned short ldsA[128 * 64];
  __shared__ unsigned short ldsB[128 * 64];

  const int tid = threadIdx.x;
  const int lane = tid & 63, wid = tid >> 6;
  const int c16 = lane & 15, g = lane >> 4;
  const int m0 = blockIdx.y * 128, n0 = blockIdx.x * 128;
  const int wr = (wid >> 1) * 64, wc = (wid & 1) * 64;

  f32x4 acc[4][4] = {};

  for (int kt = 0; kt < K; kt += 64) {
    __syncthreads();
#pragma unroll
    for (int i = 0; i < 4; ++i) {
      int row = i * 32 + (tid >> 3);
      int cc = tid & 7;
      int scc = cc ^ (row & 7);
      gload16(A + (size_t)(m0 + row) * K + kt + scc * 8, ldsA + row * 64 + cc * 8);
      gload16(B + (size_t)(n0 + row) * K + kt + scc * 8, ldsB + row * 64 + cc * 8);
    }
    __syncthreads();
#pragma unroll
    for (int kc = 0; kc < 2; ++kc) {
      short8 af[4], bf[4];
#pragma unroll
      for (int mi = 0; mi < 4; ++mi) af[mi] = fragld64(ldsA, wr + mi * 16 + c16, kc * 4 + g);
#pragma unroll
      for (int ni = 0; ni < 4; ++ni) bf[ni] = fragld64(ldsB, wc + ni * 16 + c16, kc * 4 + g);
#pragma unroll
      for (int mi = 0; mi < 4; ++mi)
#pragma unroll
        for (int ni = 0; ni < 4; ++ni)
          acc[mi][ni] = MFMA16(af[mi], bf[ni], acc[mi][ni]);
    }
  }

#pragma unroll
  for (int mi = 0; mi < 4; ++mi)
#pragma unroll
    for (int ni = 0; ni < 4; ++ni) {
      int col = n0 + wc + ni * 16 + c16;
      float bb = bias[col];
#pragma unroll
      for (int r = 0; r < 4; ++r) {
        int row = m0 + wr + mi * 16 + g * 4 + r;
        float v = (acc[mi][ni][r] + bb) * scale;
        if constexpr (OUT_BF16)
          ((unsigned short*)outv)[(size_t)z * 4194304ull + (size_t)row * N + col] = f2bf(v);
        else
          ((float*)outv)[(size_t)row * N + col] = v;
      }
    }
}

// Flash attention, swapped-QK^T softmax, QBLK=128 (4 waves x 2 q-frags of 16),
// KVBLK=64, 2-phase pipelined K/V staging (one barrier per tile, counted overlap).
// grid (sl/128, H, B). Q pre-scaled by 0.125*log2(e); softmax in exp2 domain.
// mw: mask bit-words [b][q][k/64], bit=masked.
__global__ __launch_bounds__(256, 2) void attn(
    const unsigned short* __restrict__ qh, const unsigned short* __restrict__ kh,
    const unsigned short* __restrict__ vh, const unsigned long long* __restrict__ mw,
    unsigned short* __restrict__ zout)
{
  constexpr int SL = 2048, DM = 1024, NT = SL / 64;
  const int q0 = blockIdx.x * 128;
  const int h = blockIdx.y, b = blockIdx.z;
  const int tid = threadIdx.x, lane = tid & 63, w = tid >> 6;
  const int c16 = lane & 15, g = lane >> 4;

  __shared__ unsigned short kbuf[2][4096];   // [key][d] chunks, xor-swizzled
  __shared__ unsigned short vt[2][4096];     // [d][key] chunks, xor-swizzled
  __shared__ unsigned short pbuf[4][2][1024];// per-wave per-frag P^T [q][key] chunks, swizzled

  const int qa = q0 + w * 32;

  short8 qf[2][2];
#pragma unroll
  for (int f = 0; f < 2; ++f) {
    const size_t qoff = ((size_t)b * SL + qa + f * 16 + c16) * DM + (size_t)h * 64;
    qf[f][0] = *(const short8*)(qh + qoff + g * 8);
    qf[f][1] = *(const short8*)(qh + qoff + 32 + g * 8);
  }

  f32x4 zacc[2][4] = {};
  float mrun[2], lrun[2];
  mrun[0] = mrun[1] = -INFINITY;
  lrun[0] = lrun[1] = 0.f;

  const size_t kvbase = ((size_t)b * SL) * DM + (size_t)h * 64;
  const unsigned long long* mwq0 = mw + ((size_t)b * SL + qa + c16) * (SL / 64);
  const unsigned long long* mwq1 = mwq0 + 16 * (SL / 64);

  // per-thread staging coordinates
  const int srow = tid >> 3, scc = tid & 7;          // K rows srow, srow+32
  const int vj = tid & 31, vd0 = (tid >> 5) * 8;     // V keys vj, vj+32; d-rows vd0..vd0+7

  unsigned long long mwc0 = mwq0[0], mwc1 = mwq1[0];
  short8 vr0, vr1;

  // prologue: stage tile 0 into buffer 0
  {
    const int r0 = srow, r1 = srow + 32;
    gload16(kh + kvbase + (size_t)r0 * DM + (scc ^ (r0 & 7)) * 8, kbuf[0] + r0 * 64 + scc * 8);
    gload16(kh + kvbase + (size_t)r1 * DM + (scc ^ (r1 & 7)) * 8, kbuf[0] + r1 * 64 + scc * 8);
    vr0 = *(const short8*)(vh + kvbase + (size_t)vj * DM + vd0);
    vr1 = *(const short8*)(vh + kvbase + (size_t)(vj + 32) * DM + vd0);
#pragma unroll
    for (int e = 0; e < 8; ++e) {
      int row = vd0 + e;
      vt[0][row * 64 + ((vj >> 3) ^ (row & 7)) * 8 + (vj & 7)] = (unsigned short)vr0[e];
      vt[0][row * 64 + (((vj + 32) >> 3) ^ (row & 7)) * 8 + (vj & 7)] = (unsigned short)vr1[e];
    }
  }

  for (int t = 0; t < NT; ++t) {
    const int cur = t & 1, nxt = cur ^ 1;
    __syncthreads();  // buf[cur] staged (vmcnt+lgkmcnt drained by all waves)

    const bool more = (t + 1 < NT);
    unsigned long long mwn0 = 0, mwn1 = 0;
    if (more) {  // issue next tile's loads; latency hides under compute below
      const size_t kb = kvbase + (size_t)(t + 1) * 64 * DM;
      const int r0 = srow, r1 = srow + 32;
      gload16(kh + kb + (size_t)r0 * DM + (scc ^ (r0 & 7)) * 8, kbuf[nxt] + r0 * 64 + scc * 8);
      gload16(kh + kb + (size_t)r1 * DM + (scc ^ (r1 & 7)) * 8, kbuf[nxt] + r1 * 64 + scc * 8);
      vr0 = *(const short8*)(vh + kb + (size_t)vj * DM + vd0);
      vr1 = *(const short8*)(vh + kb + (size_t)(vj + 32) * DM + vd0);
      mwn0 = mwq0[t + 1];
      mwn1 = mwq1[t + 1];
    }

    // ---- compute tile t ----
    // mask bits -> C-init (-1e10 where masked)
    f32x4 sacc[2][4];
#pragma unroll
    for (int f = 0; f < 2; ++f) {
      unsigned long long word = f ? mwc1 : mwc0;
#pragma unroll
      for (int nt = 0; nt < 4; ++nt) {
        unsigned int nib = (unsigned int)(word >> (nt * 16 + g * 4)) & 0xFu;
#pragma unroll
        for (int r = 0; r < 4; ++r)
          sacc[f][nt][r] = ((nib >> r) & 1u) ? -1e10f : 0.0f;
      }
    }
    // S^T = K * Q^T + bias  (D: row=key=g*4+r in tile nt, col=q=c16)
#pragma unroll
    for (int kc = 0; kc < 2; ++kc) {
      short8 kf[4];
#pragma unroll
      for (int nt = 0; nt < 4; ++nt) kf[nt] = fragld64(kbuf[cur], nt * 16 + c16, kc * 4 + g);
#pragma unroll
      for (int f = 0; f < 2; ++f)
#pragma unroll
        for (int nt = 0; nt < 4; ++nt)
          sacc[f][nt] = MFMA16(kf[nt], qf[f][kc], sacc[f][nt]);
    }
    // online softmax per q-frag: lane owns q=c16, 16 keys in-lane; 2-shfl butterfly
#pragma unroll
    for (int f = 0; f < 2; ++f) {
      float a0 = fmaxf(fmaxf(sacc[f][0][0], sacc[f][0][1]), fmaxf(sacc[f][0][2], sacc[f][0][3]));
      float a1 = fmaxf(fmaxf(sacc[f][1][0], sacc[f][1][1]), fmaxf(sacc[f][1][2], sacc[f][1][3]));
      float a2 = fmaxf(fmaxf(sacc[f][2][0], sacc[f][2][1]), fmaxf(sacc[f][2][2], sacc[f][2][3]));
      float a3 = fmaxf(fmaxf(sacc[f][3][0], sacc[f][3][1]), fmaxf(sacc[f][3][2], sacc[f][3][3]));
      float mx = fmaxf(fmaxf(a0, a1), fmaxf(a2, a3));
      mx = fmaxf(mx, __shfl_xor(mx, 16));
      mx = fmaxf(mx, __shfl_xor(mx, 32));
      float mnew = fmaxf(mrun[f], mx);
      float alpha = EXP2(mrun[f] - mnew);
      mrun[f] = mnew;
      float rs;
      {
        float ps[4];
#pragma unroll
        for (int nt = 0; nt < 4; ++nt) {
          float p0 = EXP2(sacc[f][nt][0] - mnew);
          float p1 = EXP2(sacc[f][nt][1] - mnew);
          float p2 = EXP2(sacc[f][nt][2] - mnew);
          float p3 = EXP2(sacc[f][nt][3] - mnew);
          sacc[f][nt][0] = p0; sacc[f][nt][1] = p1;
          sacc[f][nt][2] = p2; sacc[f][nt][3] = p3;
          ps[nt] = (p0 + p1) + (p2 + p3);
        }
        rs = (ps[0] + ps[1]) + (ps[2] + ps[3]);
      }
      rs += __shfl_xor(rs, 16);
      rs += __shfl_xor(rs, 32);
      lrun[f] = lrun[f] * alpha + rs;
      // P^T -> pbuf (swizzled chunks), paired b32 writes; same-wave DS ordering
      unsigned short* pbw = pbuf[w][f];
#pragma unroll
      for (int nt = 0; nt < 4; ++nt) {
        int key0 = nt * 16 + g * 4;
        int a16 = c16 * 64 + (((key0 >> 3) ^ (c16 & 7)) * 8) + (key0 & 7);
        unsigned int lo = (unsigned int)f2bf(sacc[f][nt][0]) | ((unsigned int)f2bf(sacc[f][nt][1]) << 16);
        unsigned int hi = (unsigned int)f2bf(sacc[f][nt][2]) | ((unsigned int)f2bf(sacc[f][nt][3]) << 16);
        *(unsigned int*)(pbw + a16) = lo;
        *(unsigned int*)(pbw + a16 + 2) = hi;
      }
      // rescale zacc rows (q_local = g*4+r) by that q's alpha
#pragma unroll
      for (int r = 0; r < 4; ++r) {
        float ar = __shfl(alpha, g * 4 + r);
        zacc[f][0][r] *= ar; zacc[f][1][r] *= ar;
        zacc[f][2][r] *= ar; zacc[f][3][r] *= ar;
      }
    }
    // z += P * V
#pragma unroll
    for (int kc = 0; kc < 2; ++kc) {
      short8 vf[4];
#pragma unroll
      for (int dt = 0; dt < 4; ++dt) vf[dt] = fragld64(vt[cur], dt * 16 + c16, kc * 4 + g);
#pragma unroll
      for (int f = 0; f < 2; ++f) {
        short8 pf = fragld64(pbuf[w][f], c16, kc * 4 + g);
#pragma unroll
        for (int dt = 0; dt < 4; ++dt)
          zacc[f][dt] = MFMA16(pf, vf[dt], zacc[f][dt]);
      }
    }
    // late V writes for tile t+1 (T14 split: loads issued early, writes after compute)
    if (more) {
#pragma unroll
      for (int e = 0; e < 8; ++e) {
        int row = vd0 + e;
        vt[nxt][row * 64 + ((vj >> 3) ^ (row & 7)) * 8 + (vj & 7)] = (unsigned short)vr0[e];
        vt[nxt][row * 64 + (((vj + 32) >> 3) ^ (row & 7)) * 8 + (vj & 7)] = (unsigned short)vr1[e];
      }
      mwc0 = mwn0;
      mwc1 = mwn1;
    }
  }

  // z / l -> bf16, layout [b][s][h*64+d]
#pragma unroll
  for (int f = 0; f < 2; ++f) {
    float invl = 1.f / lrun[f];
#pragma unroll
    for (int r = 0; r < 4; ++r) {
      float ir = __shfl(invl, g * 4 + r);
      size_t orow = ((size_t)b * SL + qa + f * 16 + g * 4 + r) * DM + (size_t)h * 64;
#pragma unroll
      for (int dt = 0; dt < 4; ++dt)
        zout[orow + dt * 16 + c16] = f2bf(zacc[f][dt][r] * ir);
    }
  }
}

extern "C" void kernel_launch(void* const* d_in, const int* in_sizes, int n_in,
                              void* d_out, int out_size, void* d_ws, size_t ws_size,
                              hipStream_t stream) {
  const float* q  = (const float*)d_in[0];
  const float* k  = (const float*)d_in[1];
  const float* v  = (const float*)d_in[2];
  const int* mask = (const int*)d_in[3];
  const float* Wq = (const float*)d_in[4];
  const float* bq = (const float*)d_in[5];
  const float* Wk = (const float*)d_in[6];
  const float* bk = (const float*)d_in[7];
  const float* Wv = (const float*)d_in[8];
  const float* bv = (const float*)d_in[9];
  const float* Wo = (const float*)d_in[10];
  const float* bo = (const float*)d_in[11];

  char* ws = (char*)d_ws;
  unsigned short* xbf = (unsigned short*)ws;              // q,k,v bf16: 24 MB (dead after QKV gemm)
  unsigned long long* mwb = (unsigned long long*)ws;      // mask bit-words: 1 MB (aliases xbf)
  unsigned short* wbf = (unsigned short*)(ws + 25165824); // Wq,Wk,Wv,Wo bf16: 8 MB
  unsigned short* qkv = (unsigned short*)(ws + 33554432); // qh,kh,vh bf16: 24 MB
  unsigned short* zbf = (unsigned short*)(ws + 58720256); // z bf16: 8 MB

  cvt3<<<dim3(4096, 1, 3), 256, 0, stream>>>(q, k, v, xbf, 1048576);
  cvt4<<<dim3(1024, 1, 4), 256, 0, stream>>>(Wq, Wk, Wv, Wo, wbf, 262144);

  // fused Q/K/V projections; Q scaled by 0.125*log2(e) (softmax in exp2 domain)
  gemm_bt<true><<<dim3(8, 32, 3), 256, 0, stream>>>(xbf, wbf, bq, bk, bv, (void*)qkv,
                                                    0.125f * 1.44269504088896f);
  // xbf now dead; pack mask bits in its place (131072 words / 16 per block)
  maskpack<<<8192, 256, 0, stream>>>(mask, mwb);
  attn<<<dim3(16, 16, 2), 256, 0, stream>>>(qkv, qkv + 4194304ull, qkv + 8388608ull, mwb, zbf);
  gemm_bt<false><<<dim3(8, 32, 1), 256, 0, stream>>>(zbf, wbf + 3145728ull, bo, bo, bo, d_out, 1.0f);
}

// Round 5
// 169.560 us; speedup vs baseline: 1.2759x; 1.0739x over previous
//
#include <hip/hip_runtime.h>

typedef __attribute__((ext_vector_type(8))) short short8;
typedef __attribute__((ext_vector_type(4))) float f32x4;

#define MFMA16(a, b, c) __builtin_amdgcn_mfma_f32_16x16x32_bf16((a), (b), (c), 0, 0, 0)

#if __has_builtin(__builtin_amdgcn_exp2f)
#define EXP2(x) __builtin_amdgcn_exp2f(x)
#else
#define EXP2(x) __expf((x) * 0.6931471805599453f)
#endif

__device__ __forceinline__ unsigned short f2bf(float f) {
  unsigned int u = __float_as_uint(f);
  u += 0x7FFFu + ((u >> 16) & 1u);   // RNE; inputs finite
  return (unsigned short)(u >> 16);
}

__device__ __forceinline__ void gload16(const void* g, void* l) {
  __builtin_amdgcn_global_load_lds((const __attribute__((address_space(1))) void*)g,
                                   (__attribute__((address_space(3))) void*)l, 16, 0, 0);
}

// Fragment read from a 64-col (128B-row) LDS tile staged with the chunk-XOR swizzle:
// LDS(row, cc) holds the tile's chunk cc^(row&7).
__device__ __forceinline__ short8 fragld64(const unsigned short* base, int row, int kchunk) {
  int cc = kchunk ^ (row & 7);
  return *(const short8*)(base + row * 64 + cc * 8);
}

// V-tile variant: extra ^(row>>3) term so scalar column-writes spread banks.
__device__ __forceinline__ short8 vfragld(const unsigned short* base, int row, int kchunk) {
  int cc = kchunk ^ (row & 7) ^ ((row >> 3) & 7);
  return *(const short8*)(base + row * 64 + cc * 8);
}

__global__ void cvt3(const float* __restrict__ a, const float* __restrict__ b,
                     const float* __restrict__ c, unsigned short* __restrict__ out, int n4) {
  const float* src = (blockIdx.z == 0) ? a : ((blockIdx.z == 1) ? b : c);
  int i = blockIdx.x * blockDim.x + threadIdx.x;
  if (i >= n4) return;
  float4 v = ((const float4*)src)[i];
  ushort4 o;
  o.x = f2bf(v.x); o.y = f2bf(v.y); o.z = f2bf(v.z); o.w = f2bf(v.w);
  ((ushort4*)(out + (size_t)blockIdx.z * (size_t)n4 * 4))[i] = o;
}

__global__ void cvt4(const float* __restrict__ a, const float* __restrict__ b,
                     const float* __restrict__ c, const float* __restrict__ d,
                     unsigned short* __restrict__ out, int n4) {
  const float* src = (blockIdx.z == 0) ? a : ((blockIdx.z == 1) ? b
                   : ((blockIdx.z == 2) ? c : d));
  int i = blockIdx.x * blockDim.x + threadIdx.x;
  if (i >= n4) return;
  float4 v = ((const float4*)src)[i];
  ushort4 o;
  o.x = f2bf(v.x); o.y = f2bf(v.y); o.z = f2bf(v.z); o.w = f2bf(v.w);
  ((ushort4*)(out + (size_t)blockIdx.z * (size_t)n4 * 4))[i] = o;
}

// mask [b][q][k] int32 -> bitmask u64 words: mw[(b*2048+q)*32 + k/64], bit i = masked.
__global__ void maskpack(const int* __restrict__ m, unsigned long long* __restrict__ mw) {
  const int lane = threadIdx.x & 63;
  const size_t wbase = ((size_t)blockIdx.x * (blockDim.x >> 6) + (threadIdx.x >> 6)) * 4ull;
#pragma unroll
  for (int u = 0; u < 4; ++u) {
    size_t word = wbase + u;
    int x = m[word * 64 + lane];
    unsigned long long bb = __ballot(x != 0);
    if (lane == 0) mw[word] = bb;
  }
}

// C[M=4096][N=1024] = A[M][K=1024] * B[N][K]^T + bias, optional scale, bf16 or f32 out.
template<bool OUT_BF16>
__global__ __launch_bounds__(256, 3) void gemm_bt(
    const unsigned short* __restrict__ Abase, const unsigned short* __restrict__ Bbase,
    const float* __restrict__ bias0, const float* __restrict__ bias1,
    const float* __restrict__ bias2, void* __restrict__ outv, float scale0)
{
  constexpr int K = 1024, N = 1024;
  const int z = blockIdx.z;
  const unsigned short* A = Abase + (size_t)z * 4194304ull;
  const unsigned short* B = Bbase + (size_t)z * 1048576ull;
  const float* bias = (z == 0) ? bias0 : ((z == 1) ? bias1 : bias2);
  const float scale = (z == 0) ? scale0 : 1.0f;

  __shared__ unsigned short ldsA[128 * 64];
  __shared__ unsigned short ldsB[128 * 64];

  const int tid = threadIdx.x;
  const int lane = tid & 63, wid = tid >> 6;
  const int c16 = lane & 15, g = lane >> 4;
  const int m0 = blockIdx.y * 128, n0 = blockIdx.x * 128;
  const int wr = (wid >> 1) * 64, wc = (wid & 1) * 64;

  f32x4 acc[4][4] = {};

  for (int kt = 0; kt < K; kt += 64) {
    __syncthreads();
#pragma unroll
    for (int i = 0; i < 4; ++i) {
      int row = i * 32 + (tid >> 3);
      int cc = tid & 7;
      int scc = cc ^ (row & 7);
      gload16(A + (size_t)(m0 + row) * K + kt + scc * 8, ldsA + row * 64 + cc * 8);
      gload16(B + (size_t)(n0 + row) * K + kt + scc * 8, ldsB + row * 64 + cc * 8);
    }
    __syncthreads();
#pragma unroll
    for (int kc = 0; kc < 2; ++kc) {
      short8 af[4], bf[4];
#pragma unroll
      for (int mi = 0; mi < 4; ++mi) af[mi] = fragld64(ldsA, wr + mi * 16 + c16, kc * 4 + g);
#pragma unroll
      for (int ni = 0; ni < 4; ++ni) bf[ni] = fragld64(ldsB, wc + ni * 16 + c16, kc * 4 + g);
#pragma unroll
      for (int mi = 0; mi < 4; ++mi)
#pragma unroll
        for (int ni = 0; ni < 4; ++ni)
          acc[mi][ni] = MFMA16(af[mi], bf[ni], acc[mi][ni]);
    }
  }

#pragma unroll
  for (int mi = 0; mi < 4; ++mi)
#pragma unroll
    for (int ni = 0; ni < 4; ++ni) {
      int col = n0 + wc + ni * 16 + c16;
      float bb = bias[col];
#pragma unroll
      for (int r = 0; r < 4; ++r) {
        int row = m0 + wr + mi * 16 + g * 4 + r;
        float v = (acc[mi][ni][r] + bb) * scale;
        if constexpr (OUT_BF16)
          ((unsigned short*)outv)[(size_t)z * 4194304ull + (size_t)row * N + col] = f2bf(v);
        else
          ((float*)outv)[(size_t)row * N + col] = v;
      }
    }
}

// Flash attention, swapped-QK^T softmax. 512 threads = 8 waves; wave w owns q rows
// [q0+16w, +16). KVBLK=64, 2-phase pipelined staging, defer-max online softmax.
// grid (sl/128, H, B). Q pre-scaled by 0.125*log2(e); softmax in exp2 domain.
__global__ __launch_bounds__(512, 4) void attn(
    const unsigned short* __restrict__ qh, const unsigned short* __restrict__ kh,
    const unsigned short* __restrict__ vh, const unsigned long long* __restrict__ mw,
    unsigned short* __restrict__ zout)
{
  constexpr int SL = 2048, DM = 1024, NT = SL / 64;
  const int q0 = blockIdx.x * 128;
  const int h = blockIdx.y, b = blockIdx.z;
  const int tid = threadIdx.x, lane = tid & 63, w = tid >> 6;
  const int c16 = lane & 15, g = lane >> 4;

  __shared__ unsigned short kbuf[2][4096];  // [key][d] chunks, xor-swizzled
  __shared__ unsigned short vt[2][4096];    // [d][key] chunks, xor^row>>3 swizzled
  __shared__ unsigned short pbuf[8][1024];  // per-wave P^T [q][key] chunks, swizzled

  const int qa = q0 + w * 16;
  const size_t qoff = ((size_t)b * SL + qa + c16) * DM + (size_t)h * 64;
  short8 qf0 = *(const short8*)(qh + qoff + g * 8);
  short8 qf1 = *(const short8*)(qh + qoff + 32 + g * 8);

  f32x4 zacc[4] = {};
  float mrun = -INFINITY, lrun = 0.f;

  const size_t kvbase = (size_t)b * SL * DM + (size_t)h * 64;
  const unsigned long long* mwq = mw + ((size_t)b * SL + qa + c16) * (SL / 64);

  const int krow = tid >> 3, kcc = tid & 7;        // K stage: one 16B chunk/thread
  const int vj = tid >> 3, vd0 = (tid & 7) * 8;    // V stage: key vj, d-rows vd0..+7

  unsigned long long mwc = mwq[0];
  short8 vr;

  // prologue: stage tile 0 into buffer 0
  gload16(kh + kvbase + (size_t)krow * DM + (kcc ^ (krow & 7)) * 8,
          kbuf[0] + krow * 64 + kcc * 8);
  vr = *(const short8*)(vh + kvbase + (size_t)vj * DM + vd0);
#pragma unroll
  for (int e = 0; e < 8; ++e) {
    int row = vd0 + e;
    int slot = (vj >> 3) ^ (row & 7) ^ ((row >> 3) & 7);
    vt[0][row * 64 + slot * 8 + (vj & 7)] = (unsigned short)vr[e];
  }

  for (int t = 0; t < NT; ++t) {
    const int cur = t & 1, nxt = cur ^ 1;
    __syncthreads();  // buf[cur] fully staged (each wave drained own vmcnt/lgkmcnt)

    const bool more = (t + 1 < NT);
    unsigned long long mwn = 0;
    if (more) {  // issue next tile's loads; latency hides under compute below
      const size_t kb = kvbase + (size_t)(t + 1) * 64 * DM;
      gload16(kh + kb + (size_t)krow * DM + (kcc ^ (krow & 7)) * 8,
              kbuf[nxt] + krow * 64 + kcc * 8);
      vr = *(const short8*)(vh + kb + (size_t)vj * DM + vd0);
      mwn = mwq[t + 1];
    }

    // ---- compute tile t ----
    // mask bits -> C-init (-1e10 where masked)
    f32x4 sacc[4];
#pragma unroll
    for (int nt = 0; nt < 4; ++nt) {
      unsigned int nib = (unsigned int)(mwc >> (nt * 16 + g * 4)) & 0xFu;
#pragma unroll
      for (int r = 0; r < 4; ++r)
        sacc[nt][r] = ((nib >> r) & 1u) ? -1e10f : 0.0f;
    }
    // S^T = K * Q^T + bias  (D: row=key=g*4+r in tile nt, col=q=c16)
#pragma unroll
    for (int kc = 0; kc < 2; ++kc) {
      short8 qfc = kc ? qf1 : qf0;
#pragma unroll
      for (int nt = 0; nt < 4; ++nt) {
        short8 kf = fragld64(kbuf[cur], nt * 16 + c16, kc * 4 + g);
        sacc[nt] = MFMA16(kf, qfc, sacc[nt]);
      }
    }

    // online softmax: lane owns q=c16 (4 g-duplicates), 16 keys in-lane
    float mx;
    {
      float a0 = fmaxf(fmaxf(sacc[0][0], sacc[0][1]), fmaxf(sacc[0][2], sacc[0][3]));
      float a1 = fmaxf(fmaxf(sacc[1][0], sacc[1][1]), fmaxf(sacc[1][2], sacc[1][3]));
      float a2 = fmaxf(fmaxf(sacc[2][0], sacc[2][1]), fmaxf(sacc[2][2], sacc[2][3]));
      float a3 = fmaxf(fmaxf(sacc[3][0], sacc[3][1]), fmaxf(sacc[3][2], sacc[3][3]));
      mx = fmaxf(fmaxf(a0, a1), fmaxf(a2, a3));
    }
    mx = fmaxf(mx, __shfl_xor(mx, 16));
    mx = fmaxf(mx, __shfl_xor(mx, 32));

    // defer-max (T13): skip rescale while tile max stays within 8 (exp2 domain)
    const bool defer = __all(mx <= mrun + 8.f) != 0;
    float mnew = defer ? mrun : fmaxf(mrun, mx);
    float rs;
    {
      float ps[4];
#pragma unroll
      for (int nt = 0; nt < 4; ++nt) {
        float p0 = EXP2(sacc[nt][0] - mnew);
        float p1 = EXP2(sacc[nt][1] - mnew);
        float p2 = EXP2(sacc[nt][2] - mnew);
        float p3 = EXP2(sacc[nt][3] - mnew);
        sacc[nt][0] = p0; sacc[nt][1] = p1; sacc[nt][2] = p2; sacc[nt][3] = p3;
        ps[nt] = (p0 + p1) + (p2 + p3);
      }
      rs = (ps[0] + ps[1]) + (ps[2] + ps[3]);
    }
    rs += __shfl_xor(rs, 16);
    rs += __shfl_xor(rs, 32);
    if (defer) {
      lrun += rs;
    } else {
      float alpha = EXP2(mrun - mnew);
      mrun = mnew;
      lrun = lrun * alpha + rs;
#pragma unroll
      for (int r = 0; r < 4; ++r) {
        float ar = __shfl(alpha, g * 4 + r);
        zacc[0][r] *= ar; zacc[1][r] *= ar; zacc[2][r] *= ar; zacc[3][r] *= ar;
      }
    }

    // pack P^T -> pbuf (swizzled chunks), one b64 write per nt
    {
      unsigned short* pbw = pbuf[w];
#pragma unroll
      for (int nt = 0; nt < 4; ++nt) {
        int key0 = nt * 16 + g * 4;
        int a16 = c16 * 64 + (((key0 >> 3) ^ (c16 & 7)) * 8) + (key0 & 7);
        unsigned long long pk =
            (unsigned long long)f2bf(sacc[nt][0])
          | ((unsigned long long)f2bf(sacc[nt][1]) << 16)
          | ((unsigned long long)f2bf(sacc[nt][2]) << 32)
          | ((unsigned long long)f2bf(sacc[nt][3]) << 48);
        *(unsigned long long*)(pbw + a16) = pk;
      }
    }

    // z += P * V  (same-wave DS ordering makes pbuf reads safe without barrier)
#pragma unroll
    for (int kc = 0; kc < 2; ++kc) {
      short8 pf = fragld64(pbuf[w], c16, kc * 4 + g);
#pragma unroll
      for (int dt = 0; dt < 4; ++dt) {
        short8 vf = vfragld(vt[cur], dt * 16 + c16, kc * 4 + g);
        zacc[dt] = MFMA16(pf, vf, zacc[dt]);
      }
    }

    // late V writes for tile t+1 (T14 split)
    if (more) {
#pragma unroll
      for (int e = 0; e < 8; ++e) {
        int row = vd0 + e;
        int slot = (vj >> 3) ^ (row & 7) ^ ((row >> 3) & 7);
        vt[nxt][row * 64 + slot * 8 + (vj & 7)] = (unsigned short)vr[e];
      }
      mwc = mwn;
    }
  }

  // z / l -> bf16, layout [b][s][h*64+d]
  float invl = 1.f / lrun;
#pragma unroll
  for (int r = 0; r < 4; ++r) {
    float ir = __shfl(invl, g * 4 + r);
    size_t orow = ((size_t)b * SL + qa + g * 4 + r) * DM + (size_t)h * 64;
#pragma unroll
    for (int dt = 0; dt < 4; ++dt)
      zout[orow + dt * 16 + c16] = f2bf(zacc[dt][r] * ir);
  }
}

extern "C" void kernel_launch(void* const* d_in, const int* in_sizes, int n_in,
                              void* d_out, int out_size, void* d_ws, size_t ws_size,
                              hipStream_t stream) {
  const float* q  = (const float*)d_in[0];
  const float* k  = (const float*)d_in[1];
  const float* v  = (const float*)d_in[2];
  const int* mask = (const int*)d_in[3];
  const float* Wq = (const float*)d_in[4];
  const float* bq = (const float*)d_in[5];
  const float* Wk = (const float*)d_in[6];
  const float* bk = (const float*)d_in[7];
  const float* Wv = (const float*)d_in[8];
  const float* bv = (const float*)d_in[9];
  const float* Wo = (const float*)d_in[10];
  const float* bo = (const float*)d_in[11];

  char* ws = (char*)d_ws;
  unsigned short* xbf = (unsigned short*)ws;              // q,k,v bf16: 24 MB (dead after QKV gemm)
  unsigned long long* mwb = (unsigned long long*)ws;      // mask bit-words: 1 MB (aliases xbf)
  unsigned short* wbf = (unsigned short*)(ws + 25165824); // Wq,Wk,Wv,Wo bf16: 8 MB
  unsigned short* qkv = (unsigned short*)(ws + 33554432); // qh,kh,vh bf16: 24 MB
  unsigned short* zbf = (unsigned short*)(ws + 58720256); // z bf16: 8 MB

  cvt3<<<dim3(4096, 1, 3), 256, 0, stream>>>(q, k, v, xbf, 1048576);
  cvt4<<<dim3(1024, 1, 4), 256, 0, stream>>>(Wq, Wk, Wv, Wo, wbf, 262144);

  // fused Q/K/V projections; Q scaled by 0.125*log2(e) (softmax in exp2 domain)
  gemm_bt<true><<<dim3(8, 32, 3), 256, 0, stream>>>(xbf, wbf, bq, bk, bv, (void*)qkv,
                                                    0.125f * 1.44269504088896f);
  // xbf now dead; pack mask bits in its place
  maskpack<<<8192, 256, 0, stream>>>(mask, mwb);
  attn<<<dim3(16, 16, 2), 512, 0, stream>>>(qkv, qkv + 4194304ull, qkv + 8388608ull, mwb, zbf);
  gemm_bt<false><<<dim3(8, 32, 1), 256, 0, stream>>>(zbf, wbf + 3145728ull, bo, bo, bo, d_out, 1.0f);
}